// Round 4
// baseline (397.956 us; speedup 1.0000x reference)
//
#include <hip/hip_runtime.h>
#include <hip/hip_bf16.h>

typedef __bf16 bf16_t;
typedef bf16_t bf16x8 __attribute__((ext_vector_type(8)));
typedef float  f32x4  __attribute__((ext_vector_type(4)));
typedef unsigned long long u64;

#define MFMA16(A,B,C) __builtin_amdgcn_mfma_f32_16x16x32_bf16((A),(B),(C),0,0,0)

// NQ=16384, NK=4096, QDIM=512, KDIM=256, MID=256

// ---------------------------------------------------------------------------
// C_bf16[M][256] = (A_f32[M][KA] @ W_f32[256][KA]^T + b[256]) * scale
// ---------------------------------------------------------------------------
template<int KA>
__global__ __launch_bounds__(256)
void proj_kernel(const float* __restrict__ A, const float* __restrict__ W,
                 const float* __restrict__ b, bf16_t* __restrict__ C,
                 float scale)
{
    __shared__ bf16_t Alds[64][40];
    __shared__ bf16_t Wlds[256][40];

    const int t  = threadIdx.x;
    const int w  = t >> 6, l = t & 63, lr = l & 15, lg = l >> 4;
    const int m0 = blockIdx.x * 64;

    f32x4 acc[16];
#pragma unroll
    for (int tt = 0; tt < 16; ++tt) acc[tt] = (f32x4){0.f, 0.f, 0.f, 0.f};

    const int ar  = t >> 2;
    const int ac8 = (t & 3) * 8;

    for (int kb = 0; kb < KA / 32; ++kb) {
        {
            const float* ap = A + (size_t)(m0 + ar) * KA + kb * 32 + ac8;
            float4 a0 = *(const float4*)ap;
            float4 a1 = *(const float4*)(ap + 4);
            bf16x8 av;
            av[0]=(bf16_t)a0.x; av[1]=(bf16_t)a0.y; av[2]=(bf16_t)a0.z; av[3]=(bf16_t)a0.w;
            av[4]=(bf16_t)a1.x; av[5]=(bf16_t)a1.y; av[6]=(bf16_t)a1.z; av[7]=(bf16_t)a1.w;
            *(bf16x8*)&Alds[ar][ac8] = av;
        }
#pragma unroll
        for (int c = 0; c < 4; ++c) {
            int e8 = c * 256 + t;
            int wr = e8 >> 2, wc8 = (e8 & 3) * 8;
            const float* wp = W + (size_t)wr * KA + kb * 32 + wc8;
            float4 w0 = *(const float4*)wp;
            float4 w1 = *(const float4*)(wp + 4);
            bf16x8 wv;
            wv[0]=(bf16_t)w0.x; wv[1]=(bf16_t)w0.y; wv[2]=(bf16_t)w0.z; wv[3]=(bf16_t)w0.w;
            wv[4]=(bf16_t)w1.x; wv[5]=(bf16_t)w1.y; wv[6]=(bf16_t)w1.z; wv[7]=(bf16_t)w1.w;
            *(bf16x8*)&Wlds[wr][wc8] = wv;
        }
        __syncthreads();

        bf16x8 af = *(bf16x8*)&Alds[w * 16 + lr][lg * 8];
#pragma unroll
        for (int tt = 0; tt < 16; ++tt) {
            bf16x8 bfrag = *(bf16x8*)&Wlds[tt * 16 + lr][lg * 8];
            acc[tt] = MFMA16(af, bfrag, acc[tt]);
        }
        __syncthreads();
    }

#pragma unroll
    for (int tt = 0; tt < 16; ++tt) {
        int col = tt * 16 + lr;
        float bias = b[col];
#pragma unroll
        for (int r = 0; r < 4; ++r) {
            int row = m0 + w * 16 + lg * 4 + r;
            C[(size_t)row * 256 + col] = (bf16_t)((acc[tt][r] + bias) * scale);
        }
    }
}

// ---------------------------------------------------------------------------
// VT[256][4096] bf16: VT[d][k] = w[k] * S[k][d]
// ---------------------------------------------------------------------------
__global__ __launch_bounds__(256)
void buildvt_kernel(const float* __restrict__ S, const float* __restrict__ wgt,
                    bf16_t* __restrict__ VT)
{
    int i = blockIdx.x * 256 + threadIdx.x;
    int d = i >> 12, k = i & 4095;
    VT[i] = (bf16_t)(wgt[k] * S[(size_t)k * 256 + d]);
}

// ---------------------------------------------------------------------------
// Bit-pack mask, 4 words per wave-iteration (4 independent loads in flight).
// ---------------------------------------------------------------------------
__global__ __launch_bounds__(256)
void maskbits_kernel(const int* __restrict__ mask, u64* __restrict__ bm)
{
    const int  lane = threadIdx.x & 63;
    const int  wid  = (blockIdx.x * 256 + threadIdx.x) >> 6;
    const int  nw   = (gridDim.x * 256) >> 6;           // 8192 waves
    const size_t NW = (size_t)16384 * 64;               // 1M words
    for (size_t w0 = (size_t)wid * 4; w0 < NW; w0 += (size_t)nw * 4) {
        int v0 = mask[(w0 + 0) * 64 + lane];
        int v1 = mask[(w0 + 1) * 64 + lane];
        int v2 = mask[(w0 + 2) * 64 + lane];
        int v3 = mask[(w0 + 3) * 64 + lane];
        u64 b0 = __ballot(v0 != 0);
        u64 b1 = __ballot(v1 != 0);
        u64 b2 = __ballot(v2 != 0);
        u64 b3 = __ballot(v3 != 0);
        if (lane < 4) {
            u64 b = lane == 0 ? b0 : lane == 1 ? b1 : lane == 2 ? b2 : b3;
            bm[w0 + lane] = b;
        }
    }
}

// ---------------------------------------------------------------------------
// Flash attention. K staged in LDS; V read DIRECT from global (L2-resident)
// with register ping-pong; P via LDS. defer-max. kv-split optional.
// grid (256, SPLIT?2:1), 256 threads = 4 waves (16 q-rows/wave).
// ---------------------------------------------------------------------------
#define VT_LOAD(buf, g)                                                        \
    _Pragma("unroll")                                                          \
    for (int j = 0; j < 8; ++j) {                                              \
        const int dt_ = (g) * 4 + (j >> 1);                                    \
        const int h_  = j & 1;                                                 \
        buf[j] = *(const bf16x8*)(VT + (size_t)(dt_ * 16 + lr) * 4096          \
                                  + kb * 64 + h_ * 32 + lg * 8);               \
    }

#define PV_MFMA(buf, g)                                                        \
    _Pragma("unroll")                                                          \
    for (int j = 0; j < 8; ++j) {                                              \
        const int dt_ = (g) * 4 + (j >> 1);                                    \
        acc[dt_] = MFMA16((j & 1) ? pa1 : pa0, buf[j], acc[dt_]);              \
    }

template<bool USE_BITS, bool SPLIT>
__global__ __launch_bounds__(256, 2)
void attn_kernel(const bf16_t* __restrict__ Qb, const bf16_t* __restrict__ Kb,
                 const bf16_t* __restrict__ VT, const int* __restrict__ mask,
                 const u64* __restrict__ bmask, float* __restrict__ out,
                 float* __restrict__ pacc, float* __restrict__ pm,
                 float* __restrict__ pl)
{
    __shared__ bf16_t Klds[64][264];    // 33.8 KB
    __shared__ bf16_t Plds[64][72];     //  9.2 KB   (43 KB total)

    const int t  = threadIdx.x;
    const int w  = t >> 6, l = t & 63, lr = l & 15, lg = l >> 4;
    const int q0 = blockIdx.x * 64;
    const int qw = q0 + w * 16;
    const int half = SPLIT ? (int)blockIdx.y : 0;
    const int kb0  = SPLIT ? half * 32 : 0;
    const int NT   = SPLIT ? 32 : 64;

    // hoist Q fragments (A-frag: row = lr, k = kk*32 + lg*8 + j)
    bf16x8 qf[8];
    {
        const bf16_t* qrow = Qb + (size_t)(qw + lr) * 256;
#pragma unroll
        for (int kk = 0; kk < 8; ++kk)
            qf[kk] = *(const bf16x8*)(qrow + kk * 32 + lg * 8);
    }

    f32x4 acc[16];
#pragma unroll
    for (int dt = 0; dt < 16; ++dt) acc[dt] = (f32x4){0.f, 0.f, 0.f, 0.f};
    float mrow[4], lsum[4];
#pragma unroll
    for (int r = 0; r < 4; ++r) { mrow[r] = -1e30f; lsum[r] = 0.f; }

    for (int tb = 0; tb < NT; ++tb) {
        const int kb = kb0 + tb;
        // ---- stage K tile [64][256]
#pragma unroll
        for (int c = 0; c < 8; ++c) {
            int e8 = c * 256 + t;
            int krow = e8 >> 5, kc8 = (e8 & 31) * 8;
            *(bf16x8*)&Klds[krow][kc8] =
                *(const bf16x8*)(Kb + (size_t)(kb * 64 + krow) * 256 + kc8);
        }
        // ---- mask for this tile
        u64 mw[4];
        int mk[4][4];
        if (USE_BITS) {
#pragma unroll
            for (int r = 0; r < 4; ++r)
                mw[r] = bmask[(size_t)(qw + lg * 4 + r) * 64 + kb];
        } else {
#pragma unroll
            for (int tt = 0; tt < 4; ++tt)
#pragma unroll
                for (int r = 0; r < 4; ++r)
                    mk[tt][r] = mask[(size_t)(qw + lg * 4 + r) * 4096 + kb * 64 + tt * 16 + lr];
        }
        __syncthreads();

        // ---- S = Q K^T (pre-scaled via Qb)
        f32x4 s[4];
#pragma unroll
        for (int tt = 0; tt < 4; ++tt) {
            f32x4 sv = (f32x4){0.f, 0.f, 0.f, 0.f};
#pragma unroll
            for (int kk = 0; kk < 8; ++kk) {
                bf16x8 kf = *(bf16x8*)&Klds[tt * 16 + lr][kk * 32 + lg * 8];
                sv = MFMA16(qf[kk], kf, sv);
            }
            s[tt] = sv;
        }
        // mask (C layout: row = lg*4+r, col = tt*16+lr)
#pragma unroll
        for (int tt = 0; tt < 4; ++tt)
#pragma unroll
            for (int r = 0; r < 4; ++r) {
                bool keep = USE_BITS ? (((mw[r] >> (tt * 16 + lr)) & 1ull) != 0)
                                     : (mk[tt][r] != 0);
                s[tt][r] = keep ? s[tt][r] : -1e30f;
            }

        // block row-max over 64 cols
        float bm[4];
#pragma unroll
        for (int r = 0; r < 4; ++r)
            bm[r] = fmaxf(fmaxf(s[0][r], s[1][r]), fmaxf(s[2][r], s[3][r]));
#pragma unroll
        for (int off = 1; off < 16; off <<= 1)
#pragma unroll
            for (int r = 0; r < 4; ++r)
                bm[r] = fmaxf(bm[r], __shfl_xor(bm[r], off));

        // defer-max: rescale only when running max grows by > 8
        bool need = false;
#pragma unroll
        for (int r = 0; r < 4; ++r) need = need || (bm[r] > mrow[r] + 8.f);
        if (__any(need)) {
#pragma unroll
            for (int r = 0; r < 4; ++r) {
                float mn = fmaxf(mrow[r], bm[r]);
                float fr = __expf(mrow[r] - mn);
                mrow[r] = mn;
                lsum[r] *= fr;
#pragma unroll
                for (int dt = 0; dt < 16; ++dt) acc[dt][r] *= fr;
            }
        }

        float pr[4][4], rs[4];
#pragma unroll
        for (int r = 0; r < 4; ++r) {
            float sum = 0.f;
#pragma unroll
            for (int tt = 0; tt < 4; ++tt) {
                float p = __expf(s[tt][r] - mrow[r]);
                pr[tt][r] = p;
                sum += p;
            }
            rs[r] = sum;
        }
#pragma unroll
        for (int off = 1; off < 16; off <<= 1)
#pragma unroll
            for (int r = 0; r < 4; ++r)
                rs[r] += __shfl_xor(rs[r], off);
#pragma unroll
        for (int r = 0; r < 4; ++r) lsum[r] += rs[r];

        // ---- issue first two VT fragment groups from global (L2-resident)
        bf16x8 vtA[8], vtB[8];
        VT_LOAD(vtA, 0);
        VT_LOAD(vtB, 1);

        // ---- P tile -> LDS (wave-private rows), overlapped with VT loads
#pragma unroll
        for (int tt = 0; tt < 4; ++tt)
#pragma unroll
            for (int r = 0; r < 4; ++r)
                Plds[w * 16 + lg * 4 + r][tt * 16 + lr] = (bf16_t)pr[tt][r];
        asm volatile("s_waitcnt lgkmcnt(0)" ::: "memory");
        __builtin_amdgcn_sched_barrier(0);

        bf16x8 pa0 = *(bf16x8*)&Plds[w * 16 + lr][lg * 8];
        bf16x8 pa1 = *(bf16x8*)&Plds[w * 16 + lr][32 + lg * 8];

        // ---- PV with register ping-pong on VT fragments
        PV_MFMA(vtA, 0);
        VT_LOAD(vtA, 2);
        PV_MFMA(vtB, 1);
        VT_LOAD(vtB, 3);
        PV_MFMA(vtA, 2);
        PV_MFMA(vtB, 3);
        __syncthreads();
    }

    if (SPLIT) {
        float* pa = pacc + (size_t)half * 16384 * 256;
#pragma unroll
        for (int r = 0; r < 4; ++r) {
            int row = qw + lg * 4 + r;
#pragma unroll
            for (int dt = 0; dt < 16; ++dt)
                pa[(size_t)row * 256 + dt * 16 + lr] = acc[dt][r];
            if (lr == 0) {
                pm[half * 16384 + row] = mrow[r];
                pl[half * 16384 + row] = lsum[r];
            }
        }
    } else {
#pragma unroll
        for (int r = 0; r < 4; ++r) {
            float inv = 1.0f / lsum[r];
#pragma unroll
            for (int dt = 0; dt < 16; ++dt)
                out[(size_t)(qw + lg * 4 + r) * 256 + dt * 16 + lr] = acc[dt][r] * inv;
        }
    }
}

// ---------------------------------------------------------------------------
// Combine the two kv-split partials.
// ---------------------------------------------------------------------------
__global__ __launch_bounds__(256)
void combine_kernel(const float* __restrict__ pacc, const float* __restrict__ pm,
                    const float* __restrict__ pl, float* __restrict__ out)
{
    int idx = blockIdx.x * 256 + threadIdx.x;
    int row = idx >> 6, c4 = (idx & 63) * 4;
    float m0 = pm[row], m1 = pm[16384 + row];
    float l0 = pl[row], l1 = pl[16384 + row];
    float m  = fmaxf(m0, m1);
    float a  = __expf(m0 - m), b = __expf(m1 - m);
    float inv = 1.0f / (l0 * a + l1 * b);
    float4 x0 = *(const float4*)(pacc + (size_t)row * 256 + c4);
    float4 x1 = *(const float4*)(pacc + (size_t)16384 * 256 + (size_t)row * 256 + c4);
    float4 o;
    o.x = (x0.x * a + x1.x * b) * inv;
    o.y = (x0.y * a + x1.y * b) * inv;
    o.z = (x0.z * a + x1.z * b) * inv;
    o.w = (x0.w * a + x1.w * b) * inv;
    *(float4*)(out + (size_t)row * 256 + c4) = o;
}

// ---------------------------------------------------------------------------
extern "C" void kernel_launch(void* const* d_in, const int* in_sizes, int n_in,
                              void* d_out, int out_size, void* d_ws, size_t ws_size,
                              hipStream_t stream)
{
    const float* gE   = (const float*)d_in[0];
    const float* sE   = (const float*)d_in[1];
    const float* wgt  = (const float*)d_in[2];
    const int*   mask = (const int*)  d_in[3];
    const float* Wq   = (const float*)d_in[4];
    const float* bq   = (const float*)d_in[5];
    const float* Wk   = (const float*)d_in[6];
    const float* bk   = (const float*)d_in[7];
    float* out = (float*)d_out;

    char* ws = (char*)d_ws;
    bf16_t* Qb = (bf16_t*)ws;                              //  8 MB @ 0
    bf16_t* Kb = (bf16_t*)(ws + 8388608);                  //  2 MB
    bf16_t* VT = (bf16_t*)(ws + 10485760);                 //  2 MB
    u64*    bm = (u64*)   (ws + 12582912);                 //  8 MB
    float*  pacc = (float*)(ws + 20971520);                // 32 MB
    float*  pm   = (float*)(ws + 54525952);                // 128 KB
    float*  pl   = (float*)(ws + 54657024);                // 128 KB
    const size_t need_full = 54788096;
    const size_t need_bits = 20971520;
    const size_t need_min  = 12582912;

    if (ws_size < need_min) return;

    proj_kernel<512><<<dim3(256, 1), 256, 0, stream>>>(gE, Wq, bq, Qb, 0.0625f);
    proj_kernel<256><<<dim3(64, 1), 256, 0, stream>>>(sE, Wk, bk, Kb, 1.0f);
    buildvt_kernel<<<4096, 256, 0, stream>>>(sE, wgt, VT);

    if (ws_size >= need_full) {
        maskbits_kernel<<<2048, 256, 0, stream>>>(mask, bm);
        attn_kernel<true, true><<<dim3(256, 2), 256, 0, stream>>>(
            Qb, Kb, VT, mask, bm, out, pacc, pm, pl);
        combine_kernel<<<4096, 256, 0, stream>>>(pacc, pm, pl, out);
    } else if (ws_size >= need_bits) {
        maskbits_kernel<<<2048, 256, 0, stream>>>(mask, bm);
        attn_kernel<true, false><<<dim3(256, 1), 256, 0, stream>>>(
            Qb, Kb, VT, mask, bm, out, nullptr, nullptr, nullptr);
    } else {
        attn_kernel<false, false><<<dim3(256, 1), 256, 0, stream>>>(
            Qb, Kb, VT, mask, bm, out, nullptr, nullptr, nullptr);
    }
}

// Round 5
// 233.266 us; speedup vs baseline: 1.7060x; 1.7060x over previous
//
#include <hip/hip_runtime.h>
#include <hip/hip_bf16.h>

typedef __bf16 bf16_t;
typedef bf16_t bf16x8 __attribute__((ext_vector_type(8)));
typedef float  f32x4  __attribute__((ext_vector_type(4)));
typedef unsigned long long u64;

#define MFMA16(A,B,C) __builtin_amdgcn_mfma_f32_16x16x32_bf16((A),(B),(C),0,0,0)

// NQ=16384, NK=4096, QDIM=512, KDIM=256, MID=256

static __device__ inline u64 shfl_xor_u64(u64 x, int off) {
    unsigned lo = (unsigned)x, hi = (unsigned)(x >> 32);
    lo = __shfl_xor(lo, off);
    hi = __shfl_xor(hi, off);
    return ((u64)hi << 32) | lo;
}

// ---------------------------------------------------------------------------
// C_bf16[M][256] = (A_f32[M][KA] @ W_f32[256][KA]^T + b[256]) * scale
// ---------------------------------------------------------------------------
template<int KA>
__global__ __launch_bounds__(256)
void proj_kernel(const float* __restrict__ A, const float* __restrict__ W,
                 const float* __restrict__ b, bf16_t* __restrict__ C,
                 float scale)
{
    __shared__ bf16_t Alds[64][40];
    __shared__ bf16_t Wlds[256][40];

    const int t  = threadIdx.x;
    const int w  = t >> 6, l = t & 63, lr = l & 15, lg = l >> 4;
    const int m0 = blockIdx.x * 64;

    f32x4 acc[16];
#pragma unroll
    for (int tt = 0; tt < 16; ++tt) acc[tt] = (f32x4){0.f, 0.f, 0.f, 0.f};

    const int ar  = t >> 2;
    const int ac8 = (t & 3) * 8;

    for (int kb = 0; kb < KA / 32; ++kb) {
        {
            const float* ap = A + (size_t)(m0 + ar) * KA + kb * 32 + ac8;
            float4 a0 = *(const float4*)ap;
            float4 a1 = *(const float4*)(ap + 4);
            bf16x8 av;
            av[0]=(bf16_t)a0.x; av[1]=(bf16_t)a0.y; av[2]=(bf16_t)a0.z; av[3]=(bf16_t)a0.w;
            av[4]=(bf16_t)a1.x; av[5]=(bf16_t)a1.y; av[6]=(bf16_t)a1.z; av[7]=(bf16_t)a1.w;
            *(bf16x8*)&Alds[ar][ac8] = av;
        }
#pragma unroll
        for (int c = 0; c < 4; ++c) {
            int e8 = c * 256 + t;
            int wr = e8 >> 2, wc8 = (e8 & 3) * 8;
            const float* wp = W + (size_t)wr * KA + kb * 32 + wc8;
            float4 w0 = *(const float4*)wp;
            float4 w1 = *(const float4*)(wp + 4);
            bf16x8 wv;
            wv[0]=(bf16_t)w0.x; wv[1]=(bf16_t)w0.y; wv[2]=(bf16_t)w0.z; wv[3]=(bf16_t)w0.w;
            wv[4]=(bf16_t)w1.x; wv[5]=(bf16_t)w1.y; wv[6]=(bf16_t)w1.z; wv[7]=(bf16_t)w1.w;
            *(bf16x8*)&Wlds[wr][wc8] = wv;
        }
        __syncthreads();

        bf16x8 af = *(bf16x8*)&Alds[w * 16 + lr][lg * 8];
#pragma unroll
        for (int tt = 0; tt < 16; ++tt) {
            bf16x8 bfrag = *(bf16x8*)&Wlds[tt * 16 + lr][lg * 8];
            acc[tt] = MFMA16(af, bfrag, acc[tt]);
        }
        __syncthreads();
    }

#pragma unroll
    for (int tt = 0; tt < 16; ++tt) {
        int col = tt * 16 + lr;
        float bias = b[col];
#pragma unroll
        for (int r = 0; r < 4; ++r) {
            int row = m0 + w * 16 + lg * 4 + r;
            C[(size_t)row * 256 + col] = (bf16_t)((acc[tt][r] + bias) * scale);
        }
    }
}

// ---------------------------------------------------------------------------
// VT[256][4096] bf16: VT[d][k] = w[k] * S[k][d]
// ---------------------------------------------------------------------------
__global__ __launch_bounds__(256)
void buildvt_kernel(const float* __restrict__ S, const float* __restrict__ wgt,
                    bf16_t* __restrict__ VT)
{
    int i = blockIdx.x * 256 + threadIdx.x;
    int d = i >> 12, k = i & 4095;
    VT[i] = (bf16_t)(wgt[k] * S[(size_t)k * 256 + d]);
}

// ---------------------------------------------------------------------------
// Flash attention (round-3 LDS structure) + INLINE mask bit-packing:
// per tile each 16-lane group reads its 4 q-rows' 64 mask ints as coalesced
// int4, packs nibbles, OR-reduces across the group -> u64 row-words in regs.
// grid (256, SPLIT?2:1), 256 threads = 4 waves (16 q-rows/wave).
// ---------------------------------------------------------------------------
template<bool SPLIT>
__global__ __launch_bounds__(256, 2)
void attn_kernel(const bf16_t* __restrict__ Qb, const bf16_t* __restrict__ Kb,
                 const bf16_t* __restrict__ VT, const int* __restrict__ mask,
                 float* __restrict__ out, float* __restrict__ pacc,
                 float* __restrict__ pm, float* __restrict__ pl)
{
    __shared__ bf16_t Klds[64][264];    // 33.8 KB
    __shared__ bf16_t VTlds[256][72];   // 36.9 KB
    __shared__ bf16_t Plds[64][72];     //  9.2 KB   (79872 B -> 2 blk/CU)

    const int t  = threadIdx.x;
    const int w  = t >> 6, l = t & 63, lr = l & 15, lg = l >> 4;
    const int q0 = blockIdx.x * 64;
    const int qw = q0 + w * 16;
    const int half = SPLIT ? (int)blockIdx.y : 0;
    const int kb0  = SPLIT ? half * 32 : 0;
    const int NT   = SPLIT ? 32 : 64;

    // hoist Q fragments (A-frag: row = lr, k = kk*32 + lg*8 + j)
    bf16x8 qf[8];
    {
        const bf16_t* qrow = Qb + (size_t)(qw + lr) * 256;
#pragma unroll
        for (int kk = 0; kk < 8; ++kk)
            qf[kk] = *(const bf16x8*)(qrow + kk * 32 + lg * 8);
    }

    f32x4 acc[16];
#pragma unroll
    for (int dt = 0; dt < 16; ++dt) acc[dt] = (f32x4){0.f, 0.f, 0.f, 0.f};
    float mrow[4], lsum[4];
#pragma unroll
    for (int r = 0; r < 4; ++r) { mrow[r] = -1e30f; lsum[r] = 0.f; }

    for (int tb = 0; tb < NT; ++tb) {
        const int kb = kb0 + tb;

        // ---- issue mask loads first (latency hides under staging)
        int4 mv[4];
#pragma unroll
        for (int r = 0; r < 4; ++r)
            mv[r] = *(const int4*)(mask + (size_t)(qw + 4 * lg + r) * 4096
                                   + kb * 64 + lr * 4);

        // ---- stage K tile [64][256]
#pragma unroll
        for (int c = 0; c < 8; ++c) {
            int e8 = c * 256 + t;
            int krow = e8 >> 5, kc8 = (e8 & 31) * 8;
            *(bf16x8*)&Klds[krow][kc8] =
                *(const bf16x8*)(Kb + (size_t)(kb * 64 + krow) * 256 + kc8);
        }
        // ---- stage VT tile [256][64]
#pragma unroll
        for (int c = 0; c < 8; ++c) {
            int e8 = c * 256 + t;
            int d = e8 >> 3, c8 = (e8 & 7) * 8;
            *(bf16x8*)&VTlds[d][c8] =
                *(const bf16x8*)(VT + (size_t)d * 4096 + kb * 64 + c8);
        }

        // ---- pack mask bits: group lg holds rows 4*lg+r; bit index == col
        u64 mw[4];
#pragma unroll
        for (int r = 0; r < 4; ++r) {
            unsigned n = (mv[r].x ? 1u : 0u) | (mv[r].y ? 2u : 0u)
                       | (mv[r].z ? 4u : 0u) | (mv[r].w ? 8u : 0u);
            u64 pw = (u64)n << (4 * lr);
#pragma unroll
            for (int off = 1; off < 16; off <<= 1)
                pw |= shfl_xor_u64(pw, off);
            mw[r] = pw;
        }
        __syncthreads();

        // ---- S = Q K^T (pre-scaled via Qb)
        f32x4 s[4];
#pragma unroll
        for (int tt = 0; tt < 4; ++tt) {
            f32x4 sv = (f32x4){0.f, 0.f, 0.f, 0.f};
#pragma unroll
            for (int kk = 0; kk < 8; ++kk) {
                bf16x8 kf = *(bf16x8*)&Klds[tt * 16 + lr][kk * 32 + lg * 8];
                sv = MFMA16(qf[kk], kf, sv);
            }
            s[tt] = sv;
        }
        // mask (C layout: row = lg*4+r, col = tt*16+lr)
#pragma unroll
        for (int tt = 0; tt < 4; ++tt)
#pragma unroll
            for (int r = 0; r < 4; ++r) {
                bool keep = ((mw[r] >> (tt * 16 + lr)) & 1ull) != 0;
                s[tt][r] = keep ? s[tt][r] : -1e30f;
            }

        // block row-max over 64 cols
        float bm[4];
#pragma unroll
        for (int r = 0; r < 4; ++r)
            bm[r] = fmaxf(fmaxf(s[0][r], s[1][r]), fmaxf(s[2][r], s[3][r]));
#pragma unroll
        for (int off = 1; off < 16; off <<= 1)
#pragma unroll
            for (int r = 0; r < 4; ++r)
                bm[r] = fmaxf(bm[r], __shfl_xor(bm[r], off));

        // defer-max: rescale only when running max grows by > 8
        bool need = false;
#pragma unroll
        for (int r = 0; r < 4; ++r) need = need || (bm[r] > mrow[r] + 8.f);
        if (__any(need)) {
#pragma unroll
            for (int r = 0; r < 4; ++r) {
                float mn = fmaxf(mrow[r], bm[r]);
                float fr = __expf(mrow[r] - mn);
                mrow[r] = mn;
                lsum[r] *= fr;
#pragma unroll
                for (int dt = 0; dt < 16; ++dt) acc[dt][r] *= fr;
            }
        }

        float pr[4][4], rs[4];
#pragma unroll
        for (int r = 0; r < 4; ++r) {
            float sum = 0.f;
#pragma unroll
            for (int tt = 0; tt < 4; ++tt) {
                float p = __expf(s[tt][r] - mrow[r]);
                pr[tt][r] = p;
                sum += p;
            }
            rs[r] = sum;
        }
#pragma unroll
        for (int off = 1; off < 16; off <<= 1)
#pragma unroll
            for (int r = 0; r < 4; ++r)
                rs[r] += __shfl_xor(rs[r], off);
#pragma unroll
        for (int r = 0; r < 4; ++r) lsum[r] += rs[r];

        // ---- P tile -> LDS (wave-private rows)
#pragma unroll
        for (int tt = 0; tt < 4; ++tt)
#pragma unroll
            for (int r = 0; r < 4; ++r)
                Plds[w * 16 + lg * 4 + r][tt * 16 + lr] = (bf16_t)pr[tt][r];
        asm volatile("s_waitcnt lgkmcnt(0)" ::: "memory");
        __builtin_amdgcn_sched_barrier(0);

        // ---- PV
        bf16x8 pa0 = *(bf16x8*)&Plds[w * 16 + lr][lg * 8];
        bf16x8 pa1 = *(bf16x8*)&Plds[w * 16 + lr][32 + lg * 8];
#pragma unroll
        for (int dt = 0; dt < 16; ++dt) {
            bf16x8 v0 = *(bf16x8*)&VTlds[dt * 16 + lr][lg * 8];
            bf16x8 v1 = *(bf16x8*)&VTlds[dt * 16 + lr][32 + lg * 8];
            acc[dt] = MFMA16(pa0, v0, acc[dt]);
            acc[dt] = MFMA16(pa1, v1, acc[dt]);
        }
        __syncthreads();
    }

    if (SPLIT) {
        float* pa = pacc + (size_t)half * 16384 * 256;
#pragma unroll
        for (int r = 0; r < 4; ++r) {
            int row = qw + lg * 4 + r;
#pragma unroll
            for (int dt = 0; dt < 16; ++dt)
                pa[(size_t)row * 256 + dt * 16 + lr] = acc[dt][r];
            if (lr == 0) {
                pm[half * 16384 + row] = mrow[r];
                pl[half * 16384 + row] = lsum[r];
            }
        }
    } else {
#pragma unroll
        for (int r = 0; r < 4; ++r) {
            float inv = 1.0f / lsum[r];
#pragma unroll
            for (int dt = 0; dt < 16; ++dt)
                out[(size_t)(qw + lg * 4 + r) * 256 + dt * 16 + lr] = acc[dt][r] * inv;
        }
    }
}

// ---------------------------------------------------------------------------
// Combine the two kv-split partials.
// ---------------------------------------------------------------------------
__global__ __launch_bounds__(256)
void combine_kernel(const float* __restrict__ pacc, const float* __restrict__ pm,
                    const float* __restrict__ pl, float* __restrict__ out)
{
    int idx = blockIdx.x * 256 + threadIdx.x;
    int row = idx >> 6, c4 = (idx & 63) * 4;
    float m0 = pm[row], m1 = pm[16384 + row];
    float l0 = pl[row], l1 = pl[16384 + row];
    float m  = fmaxf(m0, m1);
    float a  = __expf(m0 - m), b = __expf(m1 - m);
    float inv = 1.0f / (l0 * a + l1 * b);
    float4 x0 = *(const float4*)(pacc + (size_t)row * 256 + c4);
    float4 x1 = *(const float4*)(pacc + (size_t)16384 * 256 + (size_t)row * 256 + c4);
    float4 o;
    o.x = (x0.x * a + x1.x * b) * inv;
    o.y = (x0.y * a + x1.y * b) * inv;
    o.z = (x0.z * a + x1.z * b) * inv;
    o.w = (x0.w * a + x1.w * b) * inv;
    *(float4*)(out + (size_t)row * 256 + c4) = o;
}

// ---------------------------------------------------------------------------
extern "C" void kernel_launch(void* const* d_in, const int* in_sizes, int n_in,
                              void* d_out, int out_size, void* d_ws, size_t ws_size,
                              hipStream_t stream)
{
    const float* gE   = (const float*)d_in[0];
    const float* sE   = (const float*)d_in[1];
    const float* wgt  = (const float*)d_in[2];
    const int*   mask = (const int*)  d_in[3];
    const float* Wq   = (const float*)d_in[4];
    const float* bq   = (const float*)d_in[5];
    const float* Wk   = (const float*)d_in[6];
    const float* bk   = (const float*)d_in[7];
    float* out = (float*)d_out;

    char* ws = (char*)d_ws;
    bf16_t* Qb = (bf16_t*)ws;                              //  8 MB @ 0
    bf16_t* Kb = (bf16_t*)(ws + 8388608);                  //  2 MB
    bf16_t* VT = (bf16_t*)(ws + 10485760);                 //  2 MB
    float*  pacc = (float*)(ws + 12582912);                // 32 MB
    float*  pm   = (float*)(ws + 46137344);                // 128 KB
    float*  pl   = (float*)(ws + 46268416);                // 128 KB
    const size_t need_full = 46399488;
    const size_t need_min  = 12582912;

    if (ws_size < need_min) return;

    proj_kernel<512><<<dim3(256, 1), 256, 0, stream>>>(gE, Wq, bq, Qb, 0.0625f);
    proj_kernel<256><<<dim3(64, 1), 256, 0, stream>>>(sE, Wk, bk, Kb, 1.0f);
    buildvt_kernel<<<4096, 256, 0, stream>>>(sE, wgt, VT);

    if (ws_size >= need_full) {
        attn_kernel<true><<<dim3(256, 2), 256, 0, stream>>>(
            Qb, Kb, VT, mask, out, pacc, pm, pl);
        combine_kernel<<<4096, 256, 0, stream>>>(pacc, pm, pl, out);
    } else {
        attn_kernel<false><<<dim3(256, 1), 256, 0, stream>>>(
            Qb, Kb, VT, mask, out, nullptr, nullptr, nullptr);
    }
}